// Round 14
// baseline (193.827 us; speedup 1.0000x reference)
//
#include <hip/hip_runtime.h>

#define N_ 100000
#define E_ 1600000
#define HD 128
#define NB 391      // dst buckets of 256 nodes (391*256 = 100096 >= N_)
#define GB 256      // binning blocks
#define CHK 6250    // edges per binning block (256*6250 = 1.6M exact)

typedef unsigned short u16;
typedef unsigned int u32;
typedef __bf16 bf16x8 __attribute__((ext_vector_type(8)));
typedef float f32x4 __attribute__((ext_vector_type(4)));

// packed-weight offsets (u16 elements) — single bf16 plane
#define OFF_W2 0
#define OFF_W3 16384
#define OFF_WL 32768
#define OFF_P2 49152
#define OFF_P1 65536
#define PK_TOT 98304

__device__ __forceinline__ u16 f2bf(float f) {
    u32 u = __float_as_uint(f);
    return (u16)((u + 0x7FFFu + ((u >> 16) & 1u)) >> 16);
}
__device__ __forceinline__ f32x4 mfma16(uint4 a, uint4 b, f32x4 c) {
    return __builtin_amdgcn_mfma_f32_16x16x32_bf16(
        __builtin_bit_cast(bf16x8, a), __builtin_bit_cast(bf16x8, b), c, 0, 0, 0);
}

// Activation LDS layout (u16, [rows][128]): idx = row*128 + (col ^ ((row&7)<<3))
__device__ __forceinline__ uint4 ldsA(const u16* A, int row, int kt, int l) {
    int idx = row * 128 + (((kt * 32 + ((l >> 4) << 3))) ^ ((row & 7) << 3));
    return *(const uint4*)&A[idx];
}

// write C fragment (col=16*nt+(l&15), row=16*mt+4*(l>>4)+r) as ReLU'd bf16
__device__ __forceinline__ void writeActH(u16* Ah, f32x4 acc, int mt, int nt, int l) {
    const int col = nt * 16 + (l & 15);
#pragma unroll
    for (int r = 0; r < 4; ++r) {
        const int row = mt * 16 + ((l >> 4) << 2) + r;
        Ah[row * 128 + (col ^ ((row & 7) << 3))] = f2bf(fmaxf(acc[r], 0.f));
    }
}

// preload KT weight fragments (one n-tile) into registers
template<int KT>
__device__ __forceinline__ void loadW(const u16* __restrict__ wp, int nt, int l,
                                      uint4 wf[KT]) {
#pragma unroll
    for (int kt = 0; kt < KT; ++kt)
        wf[kt] = *(const uint4*)&wp[((nt * KT + kt) * 64 + l) * 8];
}

// MFMA layer with preloaded single-plane weights. MT=2 / 32-node blocks is the
// proven sweet spot (round 10: MT=4 -> 80-VGPR tier -> serialized, 2.5x slower).
template<int MT, int KT>
__device__ __forceinline__ void mfmaLayerP(const u16* Ah, const uint4 wf[KT],
                                           const float* __restrict__ bias,
                                           int nt, int l, f32x4 acc[MT])
{
    const float bv = bias[nt * 16 + (l & 15)];
#pragma unroll
    for (int mt = 0; mt < MT; ++mt) {
        acc[mt][0] = bv; acc[mt][1] = bv; acc[mt][2] = bv; acc[mt][3] = bv;
    }
#pragma unroll
    for (int kt = 0; kt < KT; ++kt)
#pragma unroll
        for (int mt = 0; mt < MT; ++mt) {
            uint4 ah = ldsA(Ah, mt * 16 + (l & 15), kt, l);
            acc[mt] = mfma16(ah, wf[kt], acc[mt]);
        }
}

// ---------------------------------------------------------------------------
// L1: pack (blocks 0..383)  ∥  bucket-count (blocks 384..639).
// count: LDS per-bucket counts of a 6250-edge chunk -> atomicAdd bucket_tot.
// ---------------------------------------------------------------------------
__global__ __launch_bounds__(256) void k_packcnt(
    const float* __restrict__ W2, const float* __restrict__ W3,
    const float* __restrict__ Wl, const float* __restrict__ P2,
    const float* __restrict__ P1, u16* __restrict__ wpk,
    const int* __restrict__ dst, int* __restrict__ bucket_tot)
{
    const int b = blockIdx.x, tid = threadIdx.x;
    if (b < 384) {
        int e = b * 256 + tid;              // e < PK_TOT always (384*256 exact)
        const float* src; int local, KT;
        if (e < OFF_P1) {
            int m = e >> 14;
            src = (m == 0) ? W2 : (m == 1) ? W3 : (m == 2) ? Wl : P2;
            local = e & 16383; KT = 4;
        } else {
            src = P1; local = e - OFF_P1; KT = 8;
        }
        int j = local & 7, lane = (local >> 3) & 63, t = local >> 9;
        int kt = t % KT, nt = t / KT;
        int k = kt * 32 + ((lane >> 4) << 3) + j;
        int n = nt * 16 + (lane & 15);
        wpk[e] = f2bf(src[k * HD + n]);
    } else {
        __shared__ int lc[NB];
        const int cb = b - 384;
        for (int i = tid; i < NB; i += 256) lc[i] = 0;
        __syncthreads();
        const int e0 = cb * CHK, e1 = min(e0 + CHK, E_);
        for (int e = e0 + tid; e < e1; e += 256)
            atomicAdd(&lc[dst[e] >> 8], 1);
        __syncthreads();
        for (int i = tid; i < NB; i += 256)
            if (lc[i]) atomicAdd(&bucket_tot[i], lc[i]);
    }
}

// ---------------------------------------------------------------------------
// layer1 (16 -> 128) VALU fp32 -> bf16 LDS. 512 thr: g=tid>>7, NPH=8.
// ---------------------------------------------------------------------------
template<int NPH>
__device__ __forceinline__ void layer1(const float xs[][16],
                                       const float* __restrict__ W1,
                                       const float* __restrict__ b1,
                                       u16* Uh, int f, int g)
{
    float w[16];
#pragma unroll
    for (int j = 0; j < 16; ++j) w[j] = W1[j * HD + f];
    const float bb = b1[f];
#pragma unroll
    for (int nn = 0; nn < NPH; ++nn) {
        const int row = g * NPH + nn;
        const float4* h4 = (const float4*)xs[row];
        float4 h0 = h4[0], h1 = h4[1], h2 = h4[2], h3 = h4[3];
        float a = bb
            + h0.x * w[0] + h0.y * w[1] + h0.z * w[2] + h0.w * w[3]
            + h1.x * w[4] + h1.y * w[5] + h1.z * w[6] + h1.w * w[7]
            + h2.x * w[8] + h2.y * w[9] + h2.z * w[10] + h2.w * w[11]
            + h3.x * w[12] + h3.y * w[13] + h3.z * w[14] + h3.w * w[15];
        Uh[row * 128 + (f ^ ((row & 7) << 3))] = f2bf(fmaxf(a, 0.f));
    }
}

// ---------------------------------------------------------------------------
// L2: msg (blocks 0..3124)  ∥  bucket scan (block 3125).
// msg: mlp_pre + lin -> msg16 + pre16; 32 nodes / 512-thread block.
// scan: exclusive prefix of bucket_tot[391] -> bucket_base[0..391], cursor.
// ---------------------------------------------------------------------------
__global__ __launch_bounds__(512) void k_msgscan(
    const float* __restrict__ x,
    const float* __restrict__ W1, const float* __restrict__ b1,
    const float* __restrict__ b2, const float* __restrict__ b3,
    const float* __restrict__ blin,
    const u16* __restrict__ wpk, u16* __restrict__ msg16,
    u16* __restrict__ pre16,
    const int* __restrict__ bucket_tot, int* __restrict__ bucket_base,
    int* __restrict__ cursor)
{
    const int tid = threadIdx.x;
    if (blockIdx.x == 3125) {
        __shared__ int s[512];
        int d = (tid < NB) ? bucket_tot[tid] : 0;
        s[tid] = d;
        __syncthreads();
        for (int st = 1; st < 512; st <<= 1) {
            int v = (tid >= st) ? s[tid - st] : 0;
            __syncthreads();
            s[tid] += v;
            __syncthreads();
        }
        if (tid <= NB) {
            int base = s[tid] - d;          // exclusive; tid==NB -> total == E_
            bucket_base[tid] = base;
            if (tid < NB) cursor[tid] = base;
        }
        return;
    }

    __shared__ float xs[32][16];
    __shared__ __align__(16) u16 Uh[4096], Vh[4096];
    const int l = tid & 63, w = tid >> 6;   // w in [0,8)
    const int base = blockIdx.x * 32;

    uint4 wf2[4];
    loadW<4>(wpk + OFF_W2, w, l, wf2);      // W2 frags land during xs/layer1

    xs[tid >> 4][tid & 15] = x[(base + (tid >> 4)) * 16 + (tid & 15)];
    __syncthreads();

    layer1<8>(xs, W1, b1, Uh, tid & 127, tid >> 7);
    __syncthreads();

    f32x4 acc[2];
    // W2: U -> V
    mfmaLayerP<2, 4>(Uh, wf2, b2, w, l, acc);
    uint4 wf3[4];
    loadW<4>(wpk + OFF_W3, w, l, wf3);      // lands during writeAct+barrier
    writeActH(Vh, acc[0], 0, w, l);
    writeActH(Vh, acc[1], 1, w, l);
    __syncthreads();

    // W3: V -> U (U = pre)
    mfmaLayerP<2, 4>(Vh, wf3, b3, w, l, acc);
    uint4 wfl[4];
    loadW<4>(wpk + OFF_WL, w, l, wfl);
    writeActH(Uh, acc[0], 0, w, l);
    writeActH(Uh, acc[1], 1, w, l);
    __syncthreads();

    // lin: U -> V (bf16 msg)
    mfmaLayerP<2, 4>(Uh, wfl, blin, w, l, acc);
    writeActH(Vh, acc[0], 0, w, l);
    writeActH(Vh, acc[1], 1, w, l);
    __syncthreads();

    // coalesced stores: msg = Vh, pre = Uh
    {
        int e = tid * 8;
        int r = e >> 7, c0 = e & 127;
        int idx = r * HD + (c0 ^ ((r & 7) << 3));
        size_t g = (size_t)(base + r) * HD + c0;
        *(uint4*)&msg16[g] = *(const uint4*)&Vh[idx];
        *(uint4*)&pre16[g] = *(const uint4*)&Uh[idx];
    }
}

// ---------------------------------------------------------------------------
// L3: scatter with per-block range reservation.
// Pass 1: LDS-count chunk; reserve [base, base+cnt) per bucket via one
// atomicAdd on the global cursor; pass 2: scatter packed edges into ebuf.
// Within-bucket order is reservation-ordered (permutes per-node fp32 sum
// order only — ulp-level, same class as the old atomic fill).
// Packed u32: (dst&255)<<24 | src  (src < 2^17).
// ---------------------------------------------------------------------------
__global__ __launch_bounds__(256) void k_scatter2(
    const int* __restrict__ src, const int* __restrict__ dst,
    int* __restrict__ cursor, u32* __restrict__ ebuf)
{
    __shared__ int lc[NB];
    __shared__ int lbase[NB];
    const int tid = threadIdx.x;
    for (int i = tid; i < NB; i += 256) lc[i] = 0;
    __syncthreads();
    const int e0 = blockIdx.x * CHK, e1 = min(e0 + CHK, E_);
    for (int e = e0 + tid; e < e1; e += 256)
        atomicAdd(&lc[dst[e] >> 8], 1);
    __syncthreads();
    for (int i = tid; i < NB; i += 256)
        lbase[i] = lc[i] ? atomicAdd(&cursor[i], lc[i]) : 0;
    __syncthreads();
    for (int e = e0 + tid; e < e1; e += 256) {
        int s = src[e], d = dst[e];
        int pos = atomicAdd(&lbase[d >> 8], 1);
        ebuf[pos] = ((u32)(d & 255) << 24) | (u32)s;
    }
}

// ---------------------------------------------------------------------------
// L4: per-bucket node offsets (LDS hist+scan) + csr fill. One block/bucket.
// ---------------------------------------------------------------------------
__global__ __launch_bounds__(256) void k_fill2(const u32* __restrict__ ebuf,
                                               const int* __restrict__ bucket_base,
                                               int* __restrict__ offs,
                                               int* __restrict__ endp,
                                               int* __restrict__ csr)
{
    __shared__ int hist[256], sc[256], cur[256];
    const int tid = threadIdx.x, b = blockIdx.x;
    const int s = bucket_base[b];
    const int e = bucket_base[b + 1];
    hist[tid] = 0;
    __syncthreads();
    for (int i = s + tid; i < e; i += 256)
        atomicAdd(&hist[ebuf[i] >> 24], 1);
    __syncthreads();
    int d = hist[tid];
    sc[tid] = d;
    __syncthreads();
    for (int st = 1; st < 256; st <<= 1) {
        int v = (tid >= st) ? sc[tid - st] : 0;
        __syncthreads();
        sc[tid] += v;
        __syncthreads();
    }
    int ex = s + sc[tid] - d;
    int node = (b << 8) + tid;
    if (node < N_) { offs[node] = ex; endp[node] = ex + d; }
    cur[tid] = ex;
    __syncthreads();
    for (int i = s + tid; i < e; i += 256) {
        u32 p = ebuf[i];
        int pos = atomicAdd(&cur[p >> 24], 1);
        csr[pos] = (int)(p & 0x00FFFFFFu);
    }
}

// ---------------------------------------------------------------------------
// L5: gather. One wave/node; quarter-wave (16 lanes) x dwordx4 covers one
// full 256 B msg row -> 4 edges in flight per load instruction.
// ---------------------------------------------------------------------------
__global__ __launch_bounds__(256) void k_agg(
    const u16* __restrict__ msg16, const int* __restrict__ csr,
    const int* __restrict__ offs, const int* __restrict__ endp,
    u32* __restrict__ agg16)
{
    const int w = threadIdx.x >> 6, l = threadIdx.x & 63;
    const int node = blockIdx.x * 4 + w;
    if (node >= N_) return;
    const int g = l >> 4;        // quarter-wave group: which edge slot
    const int c = l & 15;        // 16 B chunk within the row (cols 8c..8c+7)
    const int s = offs[node], e = endp[node];
    float a[8] = {0.f, 0.f, 0.f, 0.f, 0.f, 0.f, 0.f, 0.f};
    int i = s;
    for (; i + 16 <= e; i += 16) {
        uint4 d[4];
#pragma unroll
        for (int q = 0; q < 4; ++q) {
            int src = csr[i + 4 * q + g];
            d[q] = *(const uint4*)&msg16[(size_t)src * HD + c * 8];
        }
#pragma unroll
        for (int q = 0; q < 4; ++q) {
            const u32 dw[4] = {d[q].x, d[q].y, d[q].z, d[q].w};
#pragma unroll
            for (int j = 0; j < 4; ++j) {
                a[2 * j]     += __uint_as_float(dw[j] << 16);
                a[2 * j + 1] += __uint_as_float(dw[j] & 0xffff0000u);
            }
        }
    }
    for (; i + 4 <= e; i += 4) {
        int src = csr[i + g];
        uint4 d = *(const uint4*)&msg16[(size_t)src * HD + c * 8];
        const u32 dw[4] = {d.x, d.y, d.z, d.w};
#pragma unroll
        for (int j = 0; j < 4; ++j) {
            a[2 * j]     += __uint_as_float(dw[j] << 16);
            a[2 * j + 1] += __uint_as_float(dw[j] & 0xffff0000u);
        }
    }
    if (i < e && g < e - i) {
        int src = csr[i + g];
        uint4 d = *(const uint4*)&msg16[(size_t)src * HD + c * 8];
        const u32 dw[4] = {d.x, d.y, d.z, d.w};
#pragma unroll
        for (int j = 0; j < 4; ++j) {
            a[2 * j]     += __uint_as_float(dw[j] << 16);
            a[2 * j + 1] += __uint_as_float(dw[j] & 0xffff0000u);
        }
    }
#pragma unroll
    for (int j = 0; j < 8; ++j) {
        a[j] += __shfl_xor(a[j], 16);
        a[j] += __shfl_xor(a[j], 32);
    }
    if (g == 0) {
        uint4 o;
        o.x = ((u32)f2bf(a[1]) << 16) | (u32)f2bf(a[0]);
        o.y = ((u32)f2bf(a[3]) << 16) | (u32)f2bf(a[2]);
        o.z = ((u32)f2bf(a[5]) << 16) | (u32)f2bf(a[4]);
        o.w = ((u32)f2bf(a[7]) << 16) | (u32)f2bf(a[6]);
        *(uint4*)&agg16[(size_t)node * 64 + c * 4] = o;
    }
}

// ---------------------------------------------------------------------------
// L6: pre16 + agg16 -> P1 -> P2 -> P3 -> out.
// 32 nodes / 512-thread block. LDS 16 KB. All weight frags preloaded to regs.
// ---------------------------------------------------------------------------
__global__ __launch_bounds__(512) void k_post(
    const u16* __restrict__ pre16, const u32* __restrict__ agg16,
    const float* __restrict__ pb1, const float* __restrict__ pb2,
    const float* __restrict__ P3, const float* __restrict__ pb3,
    const u16* __restrict__ wpk, float* __restrict__ out)
{
    __shared__ __align__(16) u16 Uh[4096], Vh[4096];
    const int tid = threadIdx.x;
    const int l = tid & 63, w = tid >> 6;
    const int base = blockIdx.x * 32;

    uint4 p1f[8];
    loadW<8>(wpk + OFF_P1, w, l, p1f);      // issue first; lands during LDS fill

    {
        int e = tid * 8;
        int r = e >> 7, c0 = e & 127;
        int idx = r * HD + (c0 ^ ((r & 7) << 3));
        size_t g = (size_t)(base + r) * HD + c0;
        *(uint4*)&Uh[idx] = *(const uint4*)&pre16[g];
        *(uint4*)&Vh[idx] = *(const uint4*)&agg16[g >> 1];
    }
    __syncthreads();

    f32x4 acc[2];
    // P1 (K=256): kt 0-3 from Uh (pre), kt 4-7 from Vh (agg)
    {
        const float bv = pb1[w * 16 + (l & 15)];
        acc[0][0] = bv; acc[0][1] = bv; acc[0][2] = bv; acc[0][3] = bv;
        acc[1] = acc[0];
#pragma unroll
        for (int kt = 0; kt < 8; ++kt) {
            const u16* sh = (kt < 4) ? Uh : Vh;
#pragma unroll
            for (int mt = 0; mt < 2; ++mt) {
                uint4 ah = ldsA(sh, mt * 16 + (l & 15), kt & 3, l);
                acc[mt] = mfma16(ah, p1f[kt], acc[mt]);
            }
        }
    }
    uint4 p2f[4];
    loadW<4>(wpk + OFF_P2, w, l, p2f);      // lands during barriers+writeAct
    __syncthreads();   // all P1 reads of Uh done before overwrite
    writeActH(Uh, acc[0], 0, w, l);
    writeActH(Uh, acc[1], 1, w, l);
    __syncthreads();

    // P2: U -> V (bf16, ReLU'd)
    mfmaLayerP<2, 4>(Uh, p2f, pb2, w, l, acc);
    writeActH(Vh, acc[0], 0, w, l);
    writeActH(Vh, acc[1], 1, w, l);
    __syncthreads();

    // P3: 128 -> 16 + outer ReLU (VALU fp32; 512 thr = 32 nodes x 16 outs)
    {
        const int o = tid & 15;
        const int n = tid >> 4;
        const int sn = (n & 7) << 3;
        float a = pb3[o];
        for (int k0 = 0; k0 < HD; k0 += 8) {
            uint4 ph = *(const uint4*)&Vh[n * HD + (k0 ^ sn)];
            const u32 pw[4] = {ph.x, ph.y, ph.z, ph.w};
#pragma unroll
            for (int j = 0; j < 8; ++j) {
                u32 hv = (j & 1) ? (pw[j >> 1] & 0xffff0000u) : (pw[j >> 1] << 16);
                a += __uint_as_float(hv) * P3[(k0 + j) * 16 + o];
            }
        }
        out[(size_t)(base + n) * 16 + o] = fmaxf(a, 0.f);
    }
}

// ---------------------------------------------------------------------------
extern "C" void kernel_launch(void* const* d_in, const int* in_sizes, int n_in,
                              void* d_out, int out_size, void* d_ws, size_t ws_size,
                              hipStream_t stream)
{
    const float* x  = (const float*)d_in[0];
    const int*   ei = (const int*)d_in[1];
    const float* W1 = (const float*)d_in[2];  const float* b1  = (const float*)d_in[3];
    const float* W2 = (const float*)d_in[4];  const float* b2  = (const float*)d_in[5];
    const float* W3 = (const float*)d_in[6];  const float* b3  = (const float*)d_in[7];
    const float* Wl = (const float*)d_in[8];  const float* bl  = (const float*)d_in[9];
    const float* P1 = (const float*)d_in[10]; const float* pb1 = (const float*)d_in[11];
    const float* P2 = (const float*)d_in[12]; const float* pb2 = (const float*)d_in[13];
    const float* P3 = (const float*)d_in[14]; const float* pb3 = (const float*)d_in[15];
    float* out = (float*)d_out;

    // Workspace ~84.7 MB total
    char* ws = (char*)d_ws;
    u16* msg16  = (u16*)ws;   ws += (size_t)N_ * HD * 2;
    u32* agg16  = (u32*)ws;   ws += (size_t)N_ * 64 * 4;
    u32* ebuf   = (u32*)agg16;                   // alias: dead before k_agg writes
    int* csr    = (int*)ws;   ws += (size_t)E_ * 4;
    int* offs   = (int*)ws;   ws += (size_t)N_ * 4;
    int* endp   = (int*)ws;   ws += (size_t)N_ * 4;
    int* btot   = (int*)ws;   ws += 512 * 4;
    int* bbase  = (int*)ws;   ws += 512 * 4;
    int* cursor = (int*)ws;   ws += 512 * 4;
    u16* wpk    = (u16*)ws;   ws += (size_t)PK_TOT * 2;
    u16* pre16  = (u16*)ws;   ws += (size_t)N_ * HD * 2;

    const int* srcv = ei;
    const int* dstv = ei + E_;

    hipMemsetAsync(btot, 0, NB * 4, stream);
    k_packcnt<<<640, 256, 0, stream>>>(W2, W3, Wl, P2, P1, wpk, dstv, btot);
    k_msgscan<<<3126, 512, 0, stream>>>(x, W1, b1, b2, b3, bl, wpk, msg16, pre16,
                                        btot, bbase, cursor);
    k_scatter2<<<GB, 256, 0, stream>>>(srcv, dstv, cursor, ebuf);
    k_fill2<<<NB, 256, 0, stream>>>(ebuf, bbase, offs, endp, csr);
    k_agg<<<(N_ + 3) / 4, 256, 0, stream>>>(msg16, csr, offs, endp, agg16);
    k_post<<<N_ / 32, 512, 0, stream>>>(pre16, agg16, pb1, pb2, P3, pb3, wpk, out);
}